// Round 7
// baseline (478.604 us; speedup 1.0000x reference)
//
#include <hip/hip_runtime.h>
#include <hip/hip_cooperative_groups.h>

namespace cg = cooperative_groups;

// 3D reaction-diffusion tumor solver, 160^3 f32 grid, 30 explicit Euler steps.
// R9: persistent kernel, LDS-shared neighbors + z-quad registers.
//
// R8 post-mortem: neighbor-flag sync (no global barrier) timed 474.7us ==
// global barrier (476) == multi-launch (476.5). Sync is NOT the cost; one
// sweep intrinsically takes ~14.3us while every roofline (HBM/L2/issue) says
// ~5us -> residual is the L1/L2 request path (12 vmem/thread/step). R9 cuts
// requests+bytes: block = 640 thr = 16 y-rows x full-x x one z-QUAD (4
// contiguous planes/thread; internal z-faces from registers). Per step,
// center values are staged registers->LDS (48KB) and ym/yp/xl/xr read from
// LDS; global = 2 vec z-halo + 0.5 vec amortized y-halo per thread (12->6.5
// vmem, 112B->~42B read per 32B out). Deps shrink to 4 blocks (y+-1, z+-1).
// Triple buffer + monotone flag protocol + XCD swizzle + fallback: from R8.

#define NX 160
#define NY 160
#define NZ 160
#define NXQ (NX / 4)              // 40 float4 groups per row
#define NPLANE (NX * NY)          // 25600 floats per z-plane
#define NGROUPS (NZ * NY * NXQ)   // 1,024,000 float4 groups

// --- cooperative config: 640-thread blocks, 16y x 160x x 4z tiles ---
#define CT_BS 640
#define NYT 10                    // y-tiles (160/16)
#define NZQ 40                    // z-quads (160/4)
#define CT_NBLOCKS (NYT * NZQ)    // 400
#define LDSX 168                  // padded x: col 4+x, x-halos at 3 and 164

// --- fallback config (R2): 2 groups/thread, strided halves ---
#define FB_NTHREADS (NGROUPS / 2)      // 512,000
#define FB_NBLOCKS (FB_NTHREADS / 256) // 2000

// ---- sync + buffer state (zero-init at module load) ----
__device__ unsigned int g_flag[CT_NBLOCKS * 16];  // one flag per 64B line
__device__ float g_mid[NGROUPS * 4];              // third grid buffer (16.4MB)

__device__ __forceinline__ float4 ld4(const float* p) {
    return *reinterpret_cast<const float4*>(p);
}

// ---------------- cooperative all-steps kernel ----------------
__global__ __launch_bounds__(CT_BS) void therapy_all(
    const float* __restrict__ c_init,
    const float* __restrict__ ther,
    float* __restrict__ out,
    float* __restrict__ ws,
    const float* __restrict__ Dp,
    const float* __restrict__ rhop,
    const float* __restrict__ dtp,
    const int* __restrict__ stepsp)
{
    __shared__ float lds[4][18][LDSX];   // [plane][yrow+halo][x+pad] = 48.4KB

    // Bijective XCD swizzle (400 % 8 == 0): each XCD owns 50 contiguous
    // logical blocks = 5 whole z-quads -> halo+flag traffic mostly XCD-local.
    const int lb  = (blockIdx.x & 7) * (CT_NBLOCKS / 8) + (blockIdx.x >> 3);
    const int zq  = lb / NYT;            // 0..39
    const int yt  = lb % NYT;            // 0..9
    const int xq  = threadIdx.x % NXQ;   // 0..39
    const int yr  = threadIdx.x / NXQ;   // 0..15
    const int gy  = yt * 16 + yr;

    const int   steps   = *stepsp;
    const float D       = *Dp;
    const float rho     = *rhop;
    const float delta_t = *dtp / (float)steps;

    // Flag base: my own flag at entry (all flags advance `steps` per launch
    // -> equal at entry -> consistent across blocks, replay-safe, no reset).
    const unsigned int fbase =
        __hip_atomic_load(&g_flag[lb * 16], __ATOMIC_RELAXED,
                          __HIP_MEMORY_SCOPE_AGENT);

    const bool mzm = (zq == 0);
    const bool mzp = (zq == NZQ - 1);
    const int  offzm = mzm ? 0 : -NPLANE;
    const int  offzp = mzp ? 0 :  NPLANE;

    int b[4];
#pragma unroll
    for (int p = 0; p < 4; ++p)
        b[p] = ((4 * zq + p) * NY + gy) * NX + 4 * xq;

    // Persistent register state: therapy + current concentration (32 VGPRs).
    float4 tv[4], cv[4];
#pragma unroll
    for (int p = 0; p < 4; ++p) {
        tv[p] = ld4(ther   + b[p]);
        cv[p] = ld4(c_init + b[p]);
    }

    const float4 z4 = make_float4(0.f, 0.f, 0.f, 0.f);

    // Zero the x-halo columns once (x==-1 and x==160 are grid boundary = 0;
    // never overwritten: center writes cols 4..163, y-halo writes 4..163).
    for (int t = threadIdx.x; t < 4 * 18; t += CT_BS) {
        lds[t / 18][t % 18][3]   = 0.f;
        lds[t / 18][t % 18][164] = 0.f;
    }

    // Triple-buffer cycle; OFF aligns so step steps-1 lands in bufs[0]=out.
    float* bufs[3] = { out, ws, g_mid };
    const int OFF = (3 - (steps - 1) % 3) % 3;

    const float* rd = c_init;
    for (int i = 0; i < steps; ++i) {
        float* wr = bufs[(i + OFF) % 3];

        if (i > 0) {
            // Wait: 4 dependency blocks (y+-1, z+-1) finished step i-1.
            if (threadIdx.x < 4) {
                const int d = (threadIdx.x == 0) ? -NYT
                            : (threadIdx.x == 1) ? -1
                            : (threadIdx.x == 2) ?  1 : NYT;
                int nb = lb + d;
                nb = nb < 0 ? 0 : (nb >= CT_NBLOCKS ? CT_NBLOCKS - 1 : nb);
                const unsigned int tgt = fbase + (unsigned)i;
                while (__hip_atomic_load(&g_flag[nb * 16], __ATOMIC_RELAXED,
                                         __HIP_MEMORY_SCOPE_AGENT) < tgt) {
                    __builtin_amdgcn_s_sleep(2);
                }
            }
            __syncthreads();                 // all waves joined; LDS reusable
            __builtin_amdgcn_fence(__ATOMIC_ACQUIRE, "agent");
        }

        // ---- stage: center (registers) -> LDS; y-halo global -> LDS ----
#pragma unroll
        for (int p = 0; p < 4; ++p)
            *reinterpret_cast<float4*>(&lds[p][yr + 1][4 + 4 * xq]) = cv[p];

        if (threadIdx.x < 320) {             // 2 rows x 4 planes x 40 xq
            const int hx = threadIdx.x % 40;
            const int hp = (threadIdx.x / 40) % 4;
            const int hs = threadIdx.x / 160;        // 0 = y-1, 1 = y+16
            float4 hv = z4;
            if (!(hs == 0 && yt == 0) && !(hs == 1 && yt == NYT - 1)) {
                const int hy = yt * 16 + (hs ? 16 : -1);
                hv = ld4(rd + ((4 * zq + hp) * NY + hy) * NX + 4 * hx);
            }
            *reinterpret_cast<float4*>(&lds[hp][hs ? 17 : 0][4 + 4 * hx]) = hv;
        }

        // z-halo planes -> registers (per-thread own column, masked at edges)
        float4 zmr = ld4(rd + b[0] + offzm); if (mzm) zmr = z4;
        float4 zpr = ld4(rd + b[3] + offzp); if (mzp) zpr = z4;

        __syncthreads();

        // ---- compute 4 planes (neighbors: LDS y/x, registers z) ----
        float4 nn[4];
#pragma unroll
        for (int p = 0; p < 4; ++p) {
            const float4 ym = *reinterpret_cast<const float4*>(&lds[p][yr][4 + 4 * xq]);
            const float4 yp = *reinterpret_cast<const float4*>(&lds[p][yr + 2][4 + 4 * xq]);
            const float  xl = lds[p][yr + 1][3 + 4 * xq];
            const float  xr = lds[p][yr + 1][8 + 4 * xq];
            const float4 zl = (p == 0) ? zmr : cv[(p == 0) ? 0 : p - 1];
            const float4 zh = (p == 3) ? zpr : cv[(p == 3) ? 3 : p + 1];
            const float4 cc = cv[p];
            const float4 tm = tv[p];
            float lap, g;
            lap = xl   + cc.y + ym.x + yp.x + zl.x + zh.x - 6.f * cc.x;
            g   = D * lap + rho * cc.x * (1.f - cc.x) - 2.f * tm.x * cc.x;
            nn[p].x = fminf(fmaxf(cc.x + g * delta_t, 0.f), 1.f);
            lap = cc.x + cc.z + ym.y + yp.y + zl.y + zh.y - 6.f * cc.y;
            g   = D * lap + rho * cc.y * (1.f - cc.y) - 2.f * tm.y * cc.y;
            nn[p].y = fminf(fmaxf(cc.y + g * delta_t, 0.f), 1.f);
            lap = cc.y + cc.w + ym.z + yp.z + zl.z + zh.z - 6.f * cc.z;
            g   = D * lap + rho * cc.z * (1.f - cc.z) - 2.f * tm.z * cc.z;
            nn[p].z = fminf(fmaxf(cc.z + g * delta_t, 0.f), 1.f);
            lap = cc.z + xr   + ym.w + yp.w + zl.w + zh.w - 6.f * cc.w;
            g   = D * lap + rho * cc.w * (1.f - cc.w) - 2.f * tm.w * cc.w;
            nn[p].w = fminf(fmaxf(cc.w + g * delta_t, 0.f), 1.f);
        }
#pragma unroll
        for (int p = 0; p < 4; ++p) {
            *reinterpret_cast<float4*>(wr + b[p]) = nn[p];
            cv[p] = nn[p];
        }

        // Post progress: after the barrier every thread's stores are drained
        // (compiler emits vmcnt(0) before s_barrier); release orders them.
        __syncthreads();
        if (threadIdx.x == 0) {
            __hip_atomic_store(&g_flag[lb * 16], fbase + (unsigned)i + 1u,
                               __ATOMIC_RELEASE, __HIP_MEMORY_SCOPE_AGENT);
        }

        rd = wr;
    }
}

// ---------------- fallback per-step kernel (R2, passed @476us) ----------------
__global__ __launch_bounds__(256) void therapy_step(
    const float* __restrict__ src,
    const float* __restrict__ ther,
    float* __restrict__ dst,
    const float* __restrict__ Dp,
    const float* __restrict__ rhop,
    const float* __restrict__ dtp,
    const int* __restrict__ stepsp)
{
    const int tid = blockIdx.x * blockDim.x + threadIdx.x;

    const int xq = tid % NXQ;
    const int t2 = tid / NXQ;
    const int y  = t2 % NY;
    const int z0 = t2 / NY;             // 0..79
    const int base0 = tid * 4;          // group 0: z in [0,80)
    const int base1 = base0 + 80 * NPLANE;  // group 1: z in [80,160)

    const int offym = (y > 0)        ? -NX : 0;
    const int offyp = (y < NY - 1)   ?  NX : 0;
    const int offxl = (xq > 0)       ? -1  : 0;
    const int offxr = (xq < NXQ - 1) ?  4  : 3;
    const int offzm0 = (z0 > 0)      ? -NPLANE : 0;
    const int offzp1 = (z0 < 79)     ?  NPLANE : 0;

    const float4 cc0 = ld4(src + base0);
    const float4 cc1 = ld4(src + base1);
    float4 ym0 = ld4(src + base0 + offym);
    float4 ym1 = ld4(src + base1 + offym);
    float4 yp0 = ld4(src + base0 + offyp);
    float4 yp1 = ld4(src + base1 + offyp);
    float4 zm0 = ld4(src + base0 + offzm0);
    const float4 zm1 = ld4(src + base1 - NPLANE);
    const float4 zp0 = ld4(src + base0 + NPLANE);
    float4 zp1 = ld4(src + base1 + offzp1);
    float xl0 = src[base0 + offxl];
    float xl1 = src[base1 + offxl];
    float xr0 = src[base0 + offxr];
    float xr1 = src[base1 + offxr];
    const float4 tm0 = ld4(ther + base0);
    const float4 tm1 = ld4(ther + base1);

    const float D       = *Dp;
    const float rho     = *rhop;
    const float delta_t = *dtp / (float)(*stepsp);

    const float4 zero4 = make_float4(0.f, 0.f, 0.f, 0.f);
    if (y == 0)        { ym0 = zero4; ym1 = zero4; }
    if (y == NY - 1)   { yp0 = zero4; yp1 = zero4; }
    if (z0 == 0)       { zm0 = zero4; }
    if (z0 == 79)      { zp1 = zero4; }
    if (xq == 0)       { xl0 = 0.f; xl1 = 0.f; }
    if (xq == NXQ - 1) { xr0 = 0.f; xr1 = 0.f; }

    {
        const float lap0 = xl0   + cc0.y + ym0.x + yp0.x + zm0.x + zp0.x - 6.f * cc0.x;
        const float lap1 = cc0.x + cc0.z + ym0.y + yp0.y + zm0.y + zp0.y - 6.f * cc0.y;
        const float lap2 = cc0.y + cc0.w + ym0.z + yp0.z + zm0.z + zp0.z - 6.f * cc0.z;
        const float lap3 = cc0.z + xr0   + ym0.w + yp0.w + zm0.w + zp0.w - 6.f * cc0.w;
        float4 o;
        float g;
        g = D * lap0 + rho * cc0.x * (1.f - cc0.x) - 2.f * tm0.x * cc0.x;
        o.x = fminf(fmaxf(cc0.x + g * delta_t, 0.f), 1.f);
        g = D * lap1 + rho * cc0.y * (1.f - cc0.y) - 2.f * tm0.y * cc0.y;
        o.y = fminf(fmaxf(cc0.y + g * delta_t, 0.f), 1.f);
        g = D * lap2 + rho * cc0.z * (1.f - cc0.z) - 2.f * tm0.z * cc0.z;
        o.z = fminf(fmaxf(cc0.z + g * delta_t, 0.f), 1.f);
        g = D * lap3 + rho * cc0.w * (1.f - cc0.w) - 2.f * tm0.w * cc0.w;
        o.w = fminf(fmaxf(cc0.w + g * delta_t, 0.f), 1.f);
        *reinterpret_cast<float4*>(dst + base0) = o;
    }
    {
        const float lap0 = xl1   + cc1.y + ym1.x + yp1.x + zm1.x + zp1.x - 6.f * cc1.x;
        const float lap1 = cc1.x + cc1.z + ym1.y + yp1.y + zm1.y + zp1.y - 6.f * cc1.y;
        const float lap2 = cc1.y + cc1.w + ym1.z + yp1.z + zm1.z + zp1.z - 6.f * cc1.z;
        const float lap3 = cc1.z + xr1   + ym1.w + yp1.w + zm1.w + zp1.w - 6.f * cc1.w;
        float4 o;
        float g;
        g = D * lap0 + rho * cc1.x * (1.f - cc1.x) - 2.f * tm1.x * cc1.x;
        o.x = fminf(fmaxf(cc1.x + g * delta_t, 0.f), 1.f);
        g = D * lap1 + rho * cc1.y * (1.f - cc1.y) - 2.f * tm1.y * cc1.y;
        o.y = fminf(fmaxf(cc1.y + g * delta_t, 0.f), 1.f);
        g = D * lap2 + rho * cc1.z * (1.f - cc1.z) - 2.f * tm1.z * cc1.z;
        o.z = fminf(fmaxf(cc1.z + g * delta_t, 0.f), 1.f);
        g = D * lap3 + rho * cc1.w * (1.f - cc1.w) - 2.f * tm1.w * cc1.w;
        o.w = fminf(fmaxf(cc1.w + g * delta_t, 0.f), 1.f);
        *reinterpret_cast<float4*>(dst + base1) = o;
    }
}

extern "C" void kernel_launch(void* const* d_in, const int* in_sizes, int n_in,
                              void* d_out, int out_size, void* d_ws, size_t ws_size,
                              hipStream_t stream) {
    const float* c_init = (const float*)d_in[0];
    const float* Dp     = (const float*)d_in[1];
    const float* rhop   = (const float*)d_in[2];
    const float* dtp    = (const float*)d_in[3];
    const float* ther   = (const float*)d_in[4];
    const int*   stepsp = (const int*)d_in[5];

    float* out = (float*)d_out;
    float* wsA = (float*)d_ws;   // grid buffer (16.4 MB)

    // ---- gate the cooperative path (computed once) ----
    static int coop_ok = -1;
    if (coop_ok < 0) {
        coop_ok = 0;
        int dev = 0;
        if (hipGetDevice(&dev) == hipSuccess) {
            int coopAttr = 0, ncu = 0, maxb = 0;
            if (hipDeviceGetAttribute(&coopAttr, hipDeviceAttributeCooperativeLaunch, dev) == hipSuccess &&
                coopAttr != 0 &&
                hipDeviceGetAttribute(&ncu, hipDeviceAttributeMultiprocessorCount, dev) == hipSuccess &&
                hipOccupancyMaxActiveBlocksPerMultiprocessor(
                    &maxb, (const void*)therapy_all, CT_BS, 0) == hipSuccess &&
                (long)maxb * (long)ncu >= (long)CT_NBLOCKS) {
                coop_ok = 1;
            }
        }
    }

    if (coop_ok == 1) {
        void* args[] = {
            (void*)&c_init, (void*)&ther, (void*)&out, (void*)&wsA,
            (void*)&Dp, (void*)&rhop, (void*)&dtp, (void*)&stepsp
        };
        if (hipLaunchCooperativeKernel((void*)therapy_all,
                                       dim3(CT_NBLOCKS), dim3(CT_BS),
                                       args, 0, stream) == hipSuccess) {
            return;
        }
        coop_ok = 0;  // launch rejected -> permanent fallback
    }

    // ---- fallback: 30 per-step launches (proven R2 path) ----
    const dim3 block(256);
    const dim3 grid(FB_NBLOCKS);
    const float* src = c_init;
    for (int i = 0; i < 30; ++i) {
        float* dst = (i & 1) ? out : wsA;
        therapy_step<<<grid, block, 0, stream>>>(src, ther, dst, Dp, rhop, dtp, stepsp);
        src = dst;
    }
}

// Round 8
// 469.460 us; speedup vs baseline: 1.0195x; 1.0195x over previous
//
#include <hip/hip_runtime.h>
#include <hip/hip_cooperative_groups.h>

namespace cg = cooperative_groups;

// 3D reaction-diffusion tumor solver, 160^3 f32 grid, 30 explicit Euler steps.
// R10: persistent kernel with TEMPORAL 2-STEP FUSION (15 macro-sweeps).
//
// R6-R9 post-mortem: five structurally different implementations (launch
// grain, sync style, occupancy 24->96%, vmem 12->6.5/thread, LDS staging)
// ALL time 474+-4us = ~15.8us per sweep; every per-sweep roofline says ~5us.
// The only untested axis is the NUMBER of dependent full-grid sweeps. R10
// halves it: per macro-step each block (8y x 4z x 160x tile; 800 blocks x
// 320 threads, 4 blocks/CU) computes t+1 on its halo-1 region (10y x 6z)
// from global into LDS (40KB), then t+2 for its own cells from LDS, writing
// only t+2 to global. t+1 never hits global: barriers 29->14, HBM writes
// 492->246MB. Ring t+1 cells are recomputed by neighbors with identical FP
// ops -> bitwise-consistent. R6's proven barrier/epoch + gates + fallback.

#define NX 160
#define NY 160
#define NZ 160
#define NXQ (NX / 4)              // 40 float4 groups per row
#define NPLANE (NX * NY)          // 25600 floats per z-plane
#define NGROUPS (NZ * NY * NXQ)   // 1,024,000 float4 groups

// --- cooperative config: 320-thread blocks, 8y x 4z x 160x tiles ---
#define CT_BS 320
#define NYT 20                    // y-tiles (160/8)
#define NZQ 40                    // z-quads (160/4)
#define CT_NBLOCKS (NYT * NZQ)    // 800

// --- fallback config (R2): 2 groups/thread, strided halves ---
#define FB_NTHREADS (NGROUPS / 2)      // 512,000
#define FB_NBLOCKS (FB_NTHREADS / 256) // 2000

// ---- barrier/buffer state (zero-init at module load) ----
__device__ unsigned int g_arrive[CT_NBLOCKS * 16];  // one flag per 64B line
__device__ unsigned int g_go[8 * 16];               // per-XCD go lines
__device__ unsigned int g_epoch_base;
__device__ float g_mid[NGROUPS * 4];                // second scratch (16.4MB)

__device__ __forceinline__ void grid_barrier(unsigned int e) {
    __syncthreads();  // all block threads' stores drained (vmcnt 0)
    const int bid = blockIdx.x;
    const int tid = threadIdx.x;
    if (bid == 0) {
        if (tid == 0) {
            __hip_atomic_store(&g_arrive[0], e, __ATOMIC_RELEASE,
                               __HIP_MEMORY_SCOPE_AGENT);
        }
        for (int j = tid; j < CT_NBLOCKS; j += CT_BS) {
            while (__hip_atomic_load(&g_arrive[j * 16], __ATOMIC_RELAXED,
                                     __HIP_MEMORY_SCOPE_AGENT) < e) {}
        }
        __syncthreads();
        if (tid == 0) {
            __builtin_amdgcn_fence(__ATOMIC_ACQUIRE, "agent");
#pragma unroll
            for (int x = 0; x < 8; ++x) {
                __hip_atomic_store(&g_go[x * 16], e, __ATOMIC_RELEASE,
                                   __HIP_MEMORY_SCOPE_AGENT);
            }
        }
        __syncthreads();
    } else {
        if (tid == 0) {
            __hip_atomic_store(&g_arrive[bid * 16], e, __ATOMIC_RELEASE,
                               __HIP_MEMORY_SCOPE_AGENT);
            while (__hip_atomic_load(&g_go[(bid & 7) * 16], __ATOMIC_RELAXED,
                                     __HIP_MEMORY_SCOPE_AGENT) < e) {
                __builtin_amdgcn_s_sleep(1);
            }
            __builtin_amdgcn_fence(__ATOMIC_ACQUIRE, "agent");
        }
        __syncthreads();
    }
}

__device__ __forceinline__ float4 ld4(const float* p) {
    return *reinterpret_cast<const float4*>(p);
}

// One Euler step for a float4 column (identical FP order everywhere).
__device__ __forceinline__ float4 step_cell(
    float4 cc, float4 ym, float4 yp, float4 zm, float4 zp,
    float xl, float xr, float4 tm, float D, float rho, float delta_t)
{
    float4 o;
    float lap, g;
    lap = xl   + cc.y + ym.x + yp.x + zm.x + zp.x - 6.f * cc.x;
    g   = D * lap + rho * cc.x * (1.f - cc.x) - 2.f * tm.x * cc.x;
    o.x = fminf(fmaxf(cc.x + g * delta_t, 0.f), 1.f);
    lap = cc.x + cc.z + ym.y + yp.y + zm.y + zp.y - 6.f * cc.y;
    g   = D * lap + rho * cc.y * (1.f - cc.y) - 2.f * tm.y * cc.y;
    o.y = fminf(fmaxf(cc.y + g * delta_t, 0.f), 1.f);
    lap = cc.y + cc.w + ym.z + yp.z + zm.z + zp.z - 6.f * cc.z;
    g   = D * lap + rho * cc.z * (1.f - cc.z) - 2.f * tm.z * cc.z;
    o.z = fminf(fmaxf(cc.z + g * delta_t, 0.f), 1.f);
    lap = cc.z + xr   + ym.w + yp.w + zm.w + zp.w - 6.f * cc.w;
    g   = D * lap + rho * cc.w * (1.f - cc.w) - 2.f * tm.w * cc.w;
    o.w = fminf(fmaxf(cc.w + g * delta_t, 0.f), 1.f);
    return o;
}

// Global masked stencil step for one column base bb (coords gy, gz, hx).
__device__ __forceinline__ float4 step_global(
    const float* rd, const float* ther, int bb, int gy, int gz, int hx,
    float D, float rho, float delta_t)
{
    const float4 z4 = make_float4(0.f, 0.f, 0.f, 0.f);
    const float4 cc = ld4(rd + bb);
    float4 ym = ld4(rd + bb + ((gy > 0)      ? -NX     : 0));
    float4 yp = ld4(rd + bb + ((gy < NY - 1) ?  NX     : 0));
    float4 zm = ld4(rd + bb + ((gz > 0)      ? -NPLANE : 0));
    float4 zp = ld4(rd + bb + ((gz < NZ - 1) ?  NPLANE : 0));
    float  xl = rd[bb + ((hx > 0)       ? -1 : 0)];
    float  xr = rd[bb + ((hx < NXQ - 1) ?  4 : 3)];
    const float4 tm = ld4(ther + bb);
    if (gy == 0)       ym = z4;
    if (gy == NY - 1)  yp = z4;
    if (gz == 0)       zm = z4;
    if (gz == NZ - 1)  zp = z4;
    if (hx == 0)       xl = 0.f;
    if (hx == NXQ - 1) xr = 0.f;
    return step_cell(cc, ym, yp, zm, zp, xl, xr, tm, D, rho, delta_t);
}

// ---------------- cooperative 2-step-fused kernel ----------------
__global__ __launch_bounds__(CT_BS, 5) void therapy_all(
    const float* __restrict__ c_init,
    const float* __restrict__ ther,
    float* __restrict__ out,
    float* __restrict__ ws,
    const float* __restrict__ Dp,
    const float* __restrict__ rhop,
    const float* __restrict__ dtp,
    const int* __restrict__ stepsp)
{
    // t+1 scratch: [zz 0..5][yy 0..9][x: col 4+x, halos at 3 and 164]
    __shared__ float lds[6][10][168];   // 40,320 B -> 4 blocks/CU

    // Bijective XCD swizzle (800 % 8 == 0): each XCD owns 100 contiguous
    // logical blocks = 5 contiguous z-quads.
    const int lb = (blockIdx.x & 7) * (CT_NBLOCKS / 8) + (blockIdx.x >> 3);
    const int zq = lb / NYT;             // 0..39
    const int yt = lb % NYT;             // 0..19
    const int xq = threadIdx.x % NXQ;    // 0..39
    const int yr = threadIdx.x / NXQ;    // 0..7

    const int   steps   = *stepsp;
    const float D       = *Dp;
    const float rho     = *rhop;
    const float delta_t = *dtp / (float)steps;

    // epoch base from previous launch (coherent at dispatch boundary)
    const unsigned int ebase = g_epoch_base;

    int b[4];
#pragma unroll
    for (int p = 0; p < 4; ++p)
        b[p] = ((4 * zq + p) * NY + (8 * yt + yr)) * NX + 4 * xq;

    float4 tv[4];
#pragma unroll
    for (int p = 0; p < 4; ++p) tv[p] = ld4(ther + b[p]);

    const float4 z4 = make_float4(0.f, 0.f, 0.f, 0.f);

    // Zero LDS x-halo columns once (never overwritten; phase-1 writes 4..163).
    for (int t = threadIdx.x; t < 60; t += CT_BS) {
        lds[t / 10][t % 10][3]   = 0.f;
        lds[t / 10][t % 10][164] = 0.f;
    }

    const int NM = steps >> 1;           // fused macro-steps
    const int W  = NM + (steps & 1);     // total grid writes

    const float* rd = c_init;
    unsigned int e = ebase;

    for (int j = 0; j < NM; ++j) {
        float* wr = (j == W - 1) ? out : ((j & 1) ? g_mid : ws);

        // ---- phase 1: t+1 on the 6z x 10y x 160x region -> LDS ----
#pragma unroll
        for (int l = 0; l < 8; ++l) {
            const int idx = threadIdx.x + l * CT_BS;
            if (idx < 2400) {
                const int hx = idx % 40;
                const int yy = (idx / 40) % 10;
                const int zz = idx / 400;          // 0..5
                const int gy = 8 * yt + yy - 1;
                const int gz = 4 * zq + zz - 1;
                float4 v = z4;
                if (gy >= 0 && gy < NY && gz >= 0 && gz < NZ) {
                    const int bb = (gz * NY + gy) * NX + 4 * hx;
                    v = step_global(rd, ther, bb, gy, gz, hx, D, rho, delta_t);
                }
                *reinterpret_cast<float4*>(&lds[zz][yy][4 + 4 * hx]) = v;
            }
        }
        __syncthreads();

        // ---- phase 2: t+2 for own cells from LDS -> global ----
#pragma unroll
        for (int p = 0; p < 4; ++p) {
            const int zz = p + 1, yy = yr + 1, xc = 4 + 4 * xq;
            const float4 cc = *reinterpret_cast<const float4*>(&lds[zz][yy][xc]);
            const float4 ym = *reinterpret_cast<const float4*>(&lds[zz][yy - 1][xc]);
            const float4 yp = *reinterpret_cast<const float4*>(&lds[zz][yy + 1][xc]);
            const float4 zm = *reinterpret_cast<const float4*>(&lds[zz - 1][yy][xc]);
            const float4 zp = *reinterpret_cast<const float4*>(&lds[zz + 1][yy][xc]);
            const float  xl = lds[zz][yy][xc - 1];
            const float  xr = lds[zz][yy][xc + 4];
            const float4 n = step_cell(cc, ym, yp, zm, zp, xl, xr, tv[p],
                                       D, rho, delta_t);
            *reinterpret_cast<float4*>(wr + b[p]) = n;
        }

        rd = wr;
        if (j + 1 < W) grid_barrier(++e);   // includes __syncthreads (LDS reuse)
    }

    // ---- odd-steps tail: one single step for own cells ----
    if (steps & 1) {
        float* wr = out;                    // index W-1 by construction
#pragma unroll
        for (int p = 0; p < 4; ++p) {
            const int gy = 8 * yt + yr;
            const int gz = 4 * zq + p;
            const float4 n = step_global(rd, ther, b[p], gy, gz, xq,
                                         D, rho, delta_t);
            *reinterpret_cast<float4*>(wr + b[p]) = n;
        }
    }

    // Bump epoch base for next launch/replay (W-1 barriers used).
    if (blockIdx.x == 0 && threadIdx.x == 0 && W > 1) {
        g_epoch_base = ebase + (unsigned)(W - 1);
    }
}

// ---------------- fallback per-step kernel (R2, passed @476us) ----------------
__global__ __launch_bounds__(256) void therapy_step(
    const float* __restrict__ src,
    const float* __restrict__ ther,
    float* __restrict__ dst,
    const float* __restrict__ Dp,
    const float* __restrict__ rhop,
    const float* __restrict__ dtp,
    const int* __restrict__ stepsp)
{
    const int tid = blockIdx.x * blockDim.x + threadIdx.x;

    const int xq = tid % NXQ;
    const int t2 = tid / NXQ;
    const int y  = t2 % NY;
    const int z0 = t2 / NY;             // 0..79
    const int base0 = tid * 4;          // group 0: z in [0,80)
    const int base1 = base0 + 80 * NPLANE;  // group 1: z in [80,160)

    const int offym = (y > 0)        ? -NX : 0;
    const int offyp = (y < NY - 1)   ?  NX : 0;
    const int offxl = (xq > 0)       ? -1  : 0;
    const int offxr = (xq < NXQ - 1) ?  4  : 3;
    const int offzm0 = (z0 > 0)      ? -NPLANE : 0;
    const int offzp1 = (z0 < 79)     ?  NPLANE : 0;

    const float4 cc0 = ld4(src + base0);
    const float4 cc1 = ld4(src + base1);
    float4 ym0 = ld4(src + base0 + offym);
    float4 ym1 = ld4(src + base1 + offym);
    float4 yp0 = ld4(src + base0 + offyp);
    float4 yp1 = ld4(src + base1 + offyp);
    float4 zm0 = ld4(src + base0 + offzm0);
    const float4 zm1 = ld4(src + base1 - NPLANE);
    const float4 zp0 = ld4(src + base0 + NPLANE);
    float4 zp1 = ld4(src + base1 + offzp1);
    float xl0 = src[base0 + offxl];
    float xl1 = src[base1 + offxl];
    float xr0 = src[base0 + offxr];
    float xr1 = src[base1 + offxr];
    const float4 tm0 = ld4(ther + base0);
    const float4 tm1 = ld4(ther + base1);

    const float D       = *Dp;
    const float rho     = *rhop;
    const float delta_t = *dtp / (float)(*stepsp);

    const float4 zero4 = make_float4(0.f, 0.f, 0.f, 0.f);
    if (y == 0)        { ym0 = zero4; ym1 = zero4; }
    if (y == NY - 1)   { yp0 = zero4; yp1 = zero4; }
    if (z0 == 0)       { zm0 = zero4; }
    if (z0 == 79)      { zp1 = zero4; }
    if (xq == 0)       { xl0 = 0.f; xl1 = 0.f; }
    if (xq == NXQ - 1) { xr0 = 0.f; xr1 = 0.f; }

    {
        const float4 o = step_cell(cc0, ym0, yp0, zm0, zp0, xl0, xr0, tm0,
                                   D, rho, delta_t);
        *reinterpret_cast<float4*>(dst + base0) = o;
    }
    {
        const float4 o = step_cell(cc1, ym1, yp1, zm1, zp1, xl1, xr1, tm1,
                                   D, rho, delta_t);
        *reinterpret_cast<float4*>(dst + base1) = o;
    }
}

extern "C" void kernel_launch(void* const* d_in, const int* in_sizes, int n_in,
                              void* d_out, int out_size, void* d_ws, size_t ws_size,
                              hipStream_t stream) {
    const float* c_init = (const float*)d_in[0];
    const float* Dp     = (const float*)d_in[1];
    const float* rhop   = (const float*)d_in[2];
    const float* dtp    = (const float*)d_in[3];
    const float* ther   = (const float*)d_in[4];
    const int*   stepsp = (const int*)d_in[5];

    float* out = (float*)d_out;
    float* wsA = (float*)d_ws;   // scratch grid buffer (16.4 MB)

    // ---- gate the cooperative path (computed once) ----
    static int coop_ok = -1;
    if (coop_ok < 0) {
        coop_ok = 0;
        int dev = 0;
        if (hipGetDevice(&dev) == hipSuccess) {
            int coopAttr = 0, ncu = 0, maxb = 0;
            if (hipDeviceGetAttribute(&coopAttr, hipDeviceAttributeCooperativeLaunch, dev) == hipSuccess &&
                coopAttr != 0 &&
                hipDeviceGetAttribute(&ncu, hipDeviceAttributeMultiprocessorCount, dev) == hipSuccess &&
                hipOccupancyMaxActiveBlocksPerMultiprocessor(
                    &maxb, (const void*)therapy_all, CT_BS, 0) == hipSuccess &&
                (long)maxb * (long)ncu >= (long)CT_NBLOCKS) {
                coop_ok = 1;
            }
        }
    }

    if (coop_ok == 1) {
        void* args[] = {
            (void*)&c_init, (void*)&ther, (void*)&out, (void*)&wsA,
            (void*)&Dp, (void*)&rhop, (void*)&dtp, (void*)&stepsp
        };
        if (hipLaunchCooperativeKernel((void*)therapy_all,
                                       dim3(CT_NBLOCKS), dim3(CT_BS),
                                       args, 0, stream) == hipSuccess) {
            return;
        }
        coop_ok = 0;  // launch rejected -> permanent fallback
    }

    // ---- fallback: 30 per-step launches (proven R2 path) ----
    const dim3 block(256);
    const dim3 grid(FB_NBLOCKS);
    const float* src = c_init;
    for (int i = 0; i < 30; ++i) {
        float* dst = (i & 1) ? out : wsA;
        therapy_step<<<grid, block, 0, stream>>>(src, ther, dst, Dp, rhop, dtp, stepsp);
        src = dst;
    }
}